// Round 9
// baseline (335.811 us; speedup 1.0000x reference)
//
#include <hip/hip_runtime.h>
#include <stdint.h>

typedef unsigned short u16;
typedef __attribute__((ext_vector_type(4))) float f32x4;
typedef __attribute__((ext_vector_type(16))) float f32x16;
typedef __attribute__((ext_vector_type(8))) short bf16x8;
typedef __attribute__((ext_vector_type(4))) unsigned short u16x4;
typedef __attribute__((ext_vector_type(4))) unsigned u32x4;

static __device__ __forceinline__ u16 f2bf(float f) {
  union { float f; unsigned u; } v; v.f = f;
  unsigned r = v.u + 0x7fffu + ((v.u >> 16) & 1u);
  return (u16)(r >> 16);
}

static __device__ __forceinline__ unsigned cvtpk(float lo, float hi) {
  unsigned r;
  asm("v_cvt_pk_bf16_f32 %0, %1, %2" : "=v"(r) : "v"(lo), "v"(hi));
  return r;
}

static __device__ __forceinline__ void plane32_swap(unsigned& a, unsigned& b) {
  asm volatile("v_permlane32_swap_b32 %0, %1" : "+v"(a), "+v"(b));
}

// D = 2^S0, single v_exp_f32
static __device__ __forceinline__ float exp2_fast(float x) {
  float r;
  asm("v_exp_f32 %0, %1" : "=v"(r) : "v"(x));
  return r;
}

static __device__ __forceinline__ void load_lds16(const void* g, void* l) {
  __builtin_amdgcn_global_load_lds(
      (const __attribute__((address_space(1))) void*)g,
      (__attribute__((address_space(3))) void*)l, 16, 0, 0);
}

// ---------------- conversion kernels ----------------

__global__ __launch_bounds__(256) void cvt_f32_bf16(
    const float* __restrict__ in, u16* __restrict__ out, int n) {
  int i = blockIdx.x * 256 + threadIdx.x;
  const int n4 = n >> 2;
  for (; i < n4; i += gridDim.x * 256) {
    f32x4 v = *(const f32x4*)(in + (size_t)i * 4);
    u16x4 o = { f2bf(v[0]), f2bf(v[1]), f2bf(v[2]), f2bf(v[3]) };
    *(u16x4*)(out + (size_t)i * 4) = o;
  }
}

__global__ __launch_bounds__(256) void build_wcat(
    const float* __restrict__ Wq, const float* __restrict__ Wk,
    const float* __restrict__ Wv, u16* __restrict__ out) {
  int i = blockIdx.x * 256 + threadIdx.x;
  const int n4 = 3072 * 512;
  for (; i < n4; i += gridDim.x * 256) {
    int row = i >> 9;
    int c4 = i & 511;
    const float* src;
    if (row < 2048)       src = Wq + (size_t)row * 2048;
    else if (row < 2560)  src = Wk + (size_t)(row - 2048) * 2048;
    else                  src = Wv + (size_t)(row - 2560) * 2048;
    f32x4 v = *(const f32x4*)(src + c4 * 4);
    u16x4 o = { f2bf(v[0]), f2bf(v[1]), f2bf(v[2]), f2bf(v[3]) };
    *(u16x4*)(out + (size_t)i * 4) = o;
  }
}

// ---------------- bf16 bt-GEMM (m97 structure, 128^2, XCD-localized): C = A B^T -------
// XCD x owns bm in [4x,4x+4), bn-major inside: A-panels L2-hot, B-panels reused 4x.
__global__ __launch_bounds__(256) void gemm_bt(
    const u16* __restrict__ A, const u16* __restrict__ B,
    float* __restrict__ C, int M, int N, int K) {
  __shared__ u16 As[128 * 32];
  __shared__ u16 Bs[128 * 32];
  const int tid = threadIdx.x;
  const int lin = blockIdx.x;
  const int x = lin & 7, t = lin >> 3;
  const int bm = x * 4 + (t & 3);
  const int bn = t >> 2;
  const int w = tid >> 6, l = tid & 63;
  const int wr = w >> 1, wc = w & 1;
  const int lr = l & 15, lg = l >> 4;
  f32x4 acc[4][4] = {};
  const int srow = tid >> 2;
  const int scol = (tid & 3) << 3;
  const u16* Ag = A + (size_t)bm * 128 * K + (size_t)srow * K + scol;
  const u16* Bg = B + (size_t)bn * 128 * K + (size_t)srow * K + scol;
  u16* Asl = As + srow * 32 + scol;
  u16* Bsl = Bs + srow * 32 + scol;
  const int nk = K >> 5;
  for (int kt = 0; kt < nk; ++kt) {
    __syncthreads();
    const int ko = kt << 5;
    load_lds16(Ag + ko, Asl);
    load_lds16(Ag + (size_t)64 * K + ko, Asl + 64 * 32);
    load_lds16(Bg + ko, Bsl);
    load_lds16(Bg + (size_t)64 * K + ko, Bsl + 64 * 32);
    __syncthreads();
    bf16x8 af[4], bfr[4];
#pragma unroll
    for (int m = 0; m < 4; ++m)
      af[m] = *(const bf16x8*)&As[(wr * 64 + m * 16 + lr) * 32 + lg * 8];
#pragma unroll
    for (int n = 0; n < 4; ++n)
      bfr[n] = *(const bf16x8*)&Bs[(wc * 64 + n * 16 + lr) * 32 + lg * 8];
#pragma unroll
    for (int m = 0; m < 4; ++m)
#pragma unroll
      for (int n = 0; n < 4; ++n)
        acc[m][n] = __builtin_amdgcn_mfma_f32_16x16x32_bf16(af[m], bfr[n], acc[m][n], 0, 0, 0);
  }
#pragma unroll
  for (int m = 0; m < 4; ++m) {
    const int row = bm * 128 + wr * 64 + m * 16 + lg * 4;
#pragma unroll
    for (int n = 0; n < 4; ++n) {
      const int col = bn * 128 + wc * 64 + n * 16 + lr;
#pragma unroll
      for (int r = 0; r < 4; ++r)
        C[(size_t)(row + r) * N + col] = acc[m][n][r];
    }
  }
}

// ---------------- per-head RMSNorm + RoPE (q scaled by 1/(sqrt(128)*ln2)) -------------
__global__ __launch_bounds__(256) void norm_rope(
    const float* __restrict__ qkv, const float* __restrict__ qn_w,
    const float* __restrict__ kn_w, const float* __restrict__ cosb,
    const float* __restrict__ sinb, u16* __restrict__ qhat,
    u16* __restrict__ khat) {
  const int gw = (blockIdx.x * 256 + threadIdx.x) >> 6;
  const int lane = threadIdx.x & 63;
  const int slot = gw % 20;
  const int row = gw / 20;  // b*2048 + t
  const int t = row & 2047;
  const int b = row >> 11;
  const float* src; const float* nw; u16* dst;
  bool isq = slot < 16;
  if (isq) {
    src = qkv + (size_t)row * 3072 + slot * 128;
    nw = qn_w;
    dst = qhat + ((size_t)(b * 16 + slot) * 2048 + t) * 128;
  } else {
    src = qkv + (size_t)row * 3072 + 2048 + (slot - 16) * 128;
    nw = kn_w;
    dst = khat + ((size_t)(b * 4 + (slot - 16)) * 2048 + t) * 128;
  }
  float x1 = src[lane], x2 = src[lane + 64];
  float ss = x1 * x1 + x2 * x2;
#pragma unroll
  for (int o = 32; o; o >>= 1) ss += __shfl_xor(ss, o);
  float rs = rsqrtf(ss * (1.0f / 128.0f) + 1e-6f);
  float h1 = x1 * rs * nw[lane];
  float h2 = x2 * rs * nw[lane + 64];
  float c = cosb[t * 128 + lane], s = sinb[t * 128 + lane];
  float o1 = h1 * c - h2 * s;
  float o2 = h2 * c + h1 * s;
  if (isq) { o1 *= 0.12751744752f; o2 *= 0.12751744752f; }  // 1/(sqrt(128)*ln2)
  dst[lane] = f2bf(o1);
  dst[lane + 64] = f2bf(o2);
}

// ---------------- V transpose ----------------
__global__ __launch_bounds__(256) void v_trans(
    const float* __restrict__ qkv, u16* __restrict__ vT) {
  __shared__ u16 st[64][130];
  const int bi = blockIdx.x;
  const int tt = bi & 31;
  const int kv = (bi >> 5) & 3;
  const int b = bi >> 7;
  const int tid = threadIdx.x;
#pragma unroll
  for (int i = 0; i < 32; ++i) {
    int idx = i * 256 + tid;
    int t = idx >> 7, d = idx & 127;
    float v = qkv[(size_t)(b * 2048 + tt * 64 + t) * 3072 + 2560 + kv * 128 + d];
    st[t][d] = f2bf(v);
  }
  __syncthreads();
#pragma unroll
  for (int i = 0; i < 32; ++i) {
    int idx = i * 256 + tid;
    int d = idx >> 6, t = idx & 63;
    vT[((size_t)(b * 4 + kv) * 128 + d) * 2048 + tt * 64 + t] = st[t][d];
  }
}

// ---------------- causal GQA flash attention — BARRIER-FREE, warp-independent --------
// Each warp owns one 32-row q strip; K and V read directly from L2 into registers
// (K/V panels are 512 KB per (b,kvh), shared by 64 blocks -> cache-resident; staging
// them in LDS forced the lockstep barrier that stalled R4-R8 at ~99 us). No LDS, no
// __syncthreads. Block = 4 warps, strips {4g..4g+3} (intra-block spread <= 3 chunks);
// co-resident blocks (bi, bi+256) carry g and 15-g so per-SIMD work sums ~const.
// Swapped 32x32 QK^T per 32-kv chunk; in-register log2 softmax; cvt_pk+permlane pack.
__global__ __launch_bounds__(256) void attn(
    const u16* __restrict__ qhat, const u16* __restrict__ khat,
    const u16* __restrict__ vT, u16* __restrict__ yb) {
  const int bi = blockIdx.x;
  const int j = bi & 255;
  const int bh = j >> 3;                       // b*16 + h
  const int g = (bi < 256) ? (j & 7) : (15 - (j & 7));
  const int h = bh & 15, b = bh >> 4;
  const int kvh = h >> 2;
  const int tid = threadIdx.x;
  const int w = tid >> 6, l = tid & 63;
  const int ql = l & 31, hi = l >> 5;
  const int c = 4 * g + w;                     // this warp's 32-row strip (0..63)
  const int wq0 = c * 32;
  const int qg = wq0 + ql;

  bf16x8 qf[8];
  const u16* qp = qhat + ((size_t)(b * 16 + h) * 2048 + qg) * 128 + hi * 8;
#pragma unroll
  for (int sf = 0; sf < 8; ++sf) qf[sf] = *(const bf16x8*)(qp + 16 * sf);

  f32x16 yacc[4] = {};
  float m = -1e30f, lsum = 0.f;

  const u16* Kg = khat + (size_t)(b * 4 + kvh) * 2048 * 128;
  const u16* Vg = vT + (size_t)(b * 4 + kvh) * 128 * 2048;

  for (int jc = 0; jc <= c; ++jc) {
    const int kv0 = jc * 32;
    // QK^T for 32 kv: A-frags straight from L2 (lane reads its own K row)
    const u16* Krow = Kg + (size_t)(kv0 + ql) * 128 + hi * 8;
    f32x16 sacc = {};
    __builtin_amdgcn_s_setprio(1);
#pragma unroll
    for (int sf = 0; sf < 8; ++sf) {
      bf16x8 kf = *(const bf16x8*)(Krow + 16 * sf);
      sacc = __builtin_amdgcn_mfma_f32_32x32x16_bf16(kf, qf[sf], sacc, 0, 0, 0);
    }
    __builtin_amdgcn_s_setprio(0);
    if (jc == c) {  // diagonal chunk: kv0 == wq0, mask crow > ql
#pragma unroll
      for (int r = 0; r < 16; ++r) {
        int crow = (r & 3) + 8 * (r >> 2) + 4 * hi;
        if (crow > ql) sacc[r] = -1e30f;
      }
    }
    float pm = -1e30f;
#pragma unroll
    for (int r = 0; r < 16; ++r) pm = fmaxf(pm, sacc[r]);
    pm = fmaxf(pm, __shfl_xor(pm, 32));
    if (!__all(pm - m <= 11.0f)) {  // defer-max (log2 units, P <= 2^11)
      float mn = fmaxf(m, pm);
      float sc = exp2_fast(m - mn);
      m = mn;
      lsum *= sc;
#pragma unroll
      for (int r = 0; r < 16; ++r) {
        int row = (r & 3) + 8 * (r >> 2) + 4 * hi;
        float scr = __shfl(sc, row);
#pragma unroll
        for (int d = 0; d < 4; ++d) yacc[d][r] *= scr;
      }
    }
    float ls = 0.f;
#pragma unroll
    for (int r = 0; r < 16; ++r) {
      float e = exp2_fast(sacc[r] - m);
      sacc[r] = e;
      ls += e;
    }
    ls += __shfl_xor(ls, 32);
    lsum += ls;
    // pack P -> 2 A-frags (32 kv = 2 k-slots of 16)
    bf16x8 pa[2];
#pragma unroll
    for (int s2 = 0; s2 < 2; ++s2) {
      const int R = s2 * 8;
      unsigned P01 = cvtpk(sacc[R + 0], sacc[R + 1]);
      unsigned P23 = cvtpk(sacc[R + 2], sacc[R + 3]);
      unsigned P45 = cvtpk(sacc[R + 4], sacc[R + 5]);
      unsigned P67 = cvtpk(sacc[R + 6], sacc[R + 7]);
      plane32_swap(P01, P45);
      plane32_swap(P23, P67);
      union { u32x4 u; bf16x8 bv; } cvu;
      cvu.u[0] = P01; cvu.u[1] = P23; cvu.u[2] = P45; cvu.u[3] = P67;
      pa[s2] = cvu.bv;
    }
    // PV: V B-frags direct from L2
    const u16* Vrow = Vg + (size_t)ql * 2048 + kv0 + hi * 8;
    __builtin_amdgcn_s_setprio(1);
#pragma unroll
    for (int d = 0; d < 4; ++d) {
      bf16x8 v0 = *(const bf16x8*)(Vrow + (size_t)d * 32 * 2048);
      bf16x8 v1 = *(const bf16x8*)(Vrow + (size_t)d * 32 * 2048 + 16);
      yacc[d] = __builtin_amdgcn_mfma_f32_32x32x16_bf16(pa[0], v0, yacc[d], 0, 0, 0);
      yacc[d] = __builtin_amdgcn_mfma_f32_32x32x16_bf16(pa[1], v1, yacc[d], 0, 0, 0);
    }
    __builtin_amdgcn_s_setprio(0);
  }
  // epilogue
#pragma unroll
  for (int r = 0; r < 16; ++r) {
    int row = (r & 3) + 8 * (r >> 2) + 4 * hi;
    float li = __shfl(lsum, row);
    float inv = 1.0f / li;
    u16* yp = yb + ((size_t)(b * 2048) + wq0 + row) * 2048 + h * 128 + ql;
#pragma unroll
    for (int d = 0; d < 4; ++d) yp[d * 32] = f2bf(yacc[d][r] * inv);
  }
}

// ---------------- launcher ----------------

extern "C" void kernel_launch(void* const* d_in, const int* in_sizes, int n_in,
                              void* d_out, int out_size, void* d_ws, size_t ws_size,
                              hipStream_t stream) {
  const float* x    = (const float*)d_in[0];
  const float* Wq   = (const float*)d_in[1];
  const float* Wk   = (const float*)d_in[2];
  const float* Wv   = (const float*)d_in[3];
  const float* Wo   = (const float*)d_in[4];
  const float* qn   = (const float*)d_in[5];
  const float* kn   = (const float*)d_in[6];
  const float* cosb = (const float*)d_in[7];
  const float* sinb = (const float*)d_in[8];
  float* out = (float*)d_out;
  (void)in_sizes; (void)n_in; (void)out_size; (void)ws_size;

  char* p = (char*)d_ws;
  u16*   xb   = (u16*)p;   p += (size_t)8388608 * 2;    // x bf16 [4096,2048]
  u16*   wcat = (u16*)p;   p += (size_t)6291456 * 2;    // [3072,2048]
  u16*   wob  = (u16*)p;   p += (size_t)4194304 * 2;    // [2048,2048]
  float* qkvf = (float*)p; p += (size_t)12582912 * 4;   // [4096,3072] fp32
  u16*   qh   = (u16*)p;   p += (size_t)8388608 * 2;    // [2,16,2048,128]
  u16*   kh   = (u16*)p;   p += (size_t)2097152 * 2;    // [2,4,2048,128]
  u16*   vt   = (u16*)p;   p += (size_t)2097152 * 2;    // [2,4,128,2048]
  u16*   yb   = (u16*)p;   p += (size_t)8388608 * 2;    // [4096,2048]

  cvt_f32_bf16<<<2048, 256, 0, stream>>>(x, xb, 8388608);
  build_wcat<<<2048, 256, 0, stream>>>(Wq, Wk, Wv, wcat);
  cvt_f32_bf16<<<2048, 256, 0, stream>>>(Wo, wob, 4194304);
  gemm_bt<<<768, 256, 0, stream>>>(xb, wcat, qkvf, 4096, 3072, 2048);
  norm_rope<<<20480, 256, 0, stream>>>(qkvf, qn, kn, cosb, sinb, qh, kh);
  v_trans<<<256, 256, 0, stream>>>(qkvf, vt);
  attn<<<512, 256, 0, stream>>>(qh, kh, vt, yb);
  gemm_bt<<<512, 256, 0, stream>>>(yb, wob, out, 4096, 2048, 2048);
}

// Round 10
// 268.096 us; speedup vs baseline: 1.2526x; 1.2526x over previous
//
#include <hip/hip_runtime.h>
#include <stdint.h>

typedef unsigned short u16;
typedef __attribute__((ext_vector_type(4))) float f32x4;
typedef __attribute__((ext_vector_type(16))) float f32x16;
typedef __attribute__((ext_vector_type(8))) short bf16x8;
typedef __attribute__((ext_vector_type(4))) unsigned short u16x4;
typedef __attribute__((ext_vector_type(4))) unsigned u32x4;

static __device__ __forceinline__ u16 f2bf(float f) {
  union { float f; unsigned u; } v; v.f = f;
  unsigned r = v.u + 0x7fffu + ((v.u >> 16) & 1u);
  return (u16)(r >> 16);
}
static __device__ __forceinline__ float bf2f(u16 u) {
  union { unsigned u; float f; } v; v.u = ((unsigned)u) << 16;
  return v.f;
}

static __device__ __forceinline__ unsigned cvtpk(float lo, float hi) {
  unsigned r;
  asm("v_cvt_pk_bf16_f32 %0, %1, %2" : "=v"(r) : "v"(lo), "v"(hi));
  return r;
}

static __device__ __forceinline__ void plane32_swap(unsigned& a, unsigned& b) {
  asm volatile("v_permlane32_swap_b32 %0, %1" : "+v"(a), "+v"(b));
}

static __device__ __forceinline__ float exp2_fast(float x) {
  float r;
  asm("v_exp_f32 %0, %1" : "=v"(r) : "v"(x));
  return r;
}

static __device__ __forceinline__ void load_lds16(const void* g, void* l) {
  __builtin_amdgcn_global_load_lds(
      (const __attribute__((address_space(1))) void*)g,
      (__attribute__((address_space(3))) void*)l, 16, 0, 0);
}

// ---------------- conversion kernels ----------------

__global__ __launch_bounds__(256) void cvt_f32_bf16(
    const float* __restrict__ in, u16* __restrict__ out, int n) {
  int i = blockIdx.x * 256 + threadIdx.x;
  const int n4 = n >> 2;
  for (; i < n4; i += gridDim.x * 256) {
    f32x4 v = *(const f32x4*)(in + (size_t)i * 4);
    u16x4 o = { f2bf(v[0]), f2bf(v[1]), f2bf(v[2]), f2bf(v[3]) };
    *(u16x4*)(out + (size_t)i * 4) = o;
  }
}

__global__ __launch_bounds__(256) void build_wcat(
    const float* __restrict__ Wq, const float* __restrict__ Wk,
    const float* __restrict__ Wv, u16* __restrict__ out) {
  int i = blockIdx.x * 256 + threadIdx.x;
  const int n4 = 3072 * 512;
  for (; i < n4; i += gridDim.x * 256) {
    int row = i >> 9;
    int c4 = i & 511;
    const float* src;
    if (row < 2048)       src = Wq + (size_t)row * 2048;
    else if (row < 2560)  src = Wk + (size_t)(row - 2048) * 2048;
    else                  src = Wv + (size_t)(row - 2560) * 2048;
    f32x4 v = *(const f32x4*)(src + c4 * 4);
    u16x4 o = { f2bf(v[0]), f2bf(v[1]), f2bf(v[2]), f2bf(v[3]) };
    *(u16x4*)(out + (size_t)i * 4) = o;
  }
}

// ---------------- fused QKV GEMM + RMSNorm + RoPE + V-transpose ----------------------
// C-tile (bm: 128 tokens, bn: one head's 128 dims) contains full head vectors, so the
// whole post-projection pipeline is tile-local. Main loop = m97 gemm_bt. Epilogue:
// row sum-of-squares (shfl over lr + 2-slot LDS cross-wave), bf16 tile in LDS [128][130]
// (stride 65 dwords: rows AND columns conflict-free), then flat pass applies
// rsqrt*w + rope (+q-scale incl. 1/ln2) and writes qh/kh coalesced, vt transposed.
__global__ __launch_bounds__(256) void gemm_qkv(
    const u16* __restrict__ A, const u16* __restrict__ W,
    const float* __restrict__ qn_w, const float* __restrict__ kn_w,
    const float* __restrict__ cosb, const float* __restrict__ sinb,
    u16* __restrict__ qh, u16* __restrict__ kh, u16* __restrict__ vt) {
  const int K = 2048;
  __shared__ u16 smem[128 * 130];          // As[0,4096) Bs[4096,8192); epilogue tile
  __shared__ float ssbuf[128][2];
  u16* As = smem;
  u16* Bs = smem + 4096;
  const int tid = threadIdx.x;
  const int lin = blockIdx.x;              // 768 blocks
  const int x = lin & 7, t = lin >> 3;     // XCD-localized: bm panel per XCD
  const int bm = x * 4 + (t & 3);          // 0..31 token block
  const int bn = t >> 2;                   // 0..23 head block
  const int w = tid >> 6, l = tid & 63;
  const int wr = w >> 1, wc = w & 1;
  const int lr = l & 15, lg = l >> 4;
  f32x4 acc[4][4] = {};
  const int srow = tid >> 2;
  const int scol = (tid & 3) << 3;
  const u16* Ag = A + (size_t)bm * 128 * K + (size_t)srow * K + scol;
  const u16* Bg = W + (size_t)bn * 128 * K + (size_t)srow * K + scol;
  u16* Asl = As + srow * 32 + scol;
  u16* Bsl = Bs + srow * 32 + scol;
  for (int kt = 0; kt < 64; ++kt) {
    __syncthreads();
    const int ko = kt << 5;
    load_lds16(Ag + ko, Asl);
    load_lds16(Ag + (size_t)64 * K + ko, Asl + 64 * 32);
    load_lds16(Bg + ko, Bsl);
    load_lds16(Bg + (size_t)64 * K + ko, Bsl + 64 * 32);
    __syncthreads();
    bf16x8 af[4], bfr[4];
#pragma unroll
    for (int m = 0; m < 4; ++m)
      af[m] = *(const bf16x8*)&As[(wr * 64 + m * 16 + lr) * 32 + lg * 8];
#pragma unroll
    for (int n = 0; n < 4; ++n)
      bfr[n] = *(const bf16x8*)&Bs[(wc * 64 + n * 16 + lr) * 32 + lg * 8];
#pragma unroll
    for (int m = 0; m < 4; ++m)
#pragma unroll
      for (int n = 0; n < 4; ++n)
        acc[m][n] = __builtin_amdgcn_mfma_f32_16x16x32_bf16(af[m], bfr[n], acc[m][n], 0, 0, 0);
  }
  __syncthreads();  // all As/Bs reads done before tile overwrites them
  // per-row sum of squares (q/k heads only)
  if (bn < 20) {
#pragma unroll
    for (int m = 0; m < 4; ++m)
#pragma unroll
      for (int r = 0; r < 4; ++r) {
        float ps = 0.f;
#pragma unroll
        for (int n = 0; n < 4; ++n) ps += acc[m][n][r] * acc[m][n][r];
#pragma unroll
        for (int o = 8; o; o >>= 1) ps += __shfl_xor(ps, o);  // over 16 lr lanes
        if (lr == 0) ssbuf[wr * 64 + m * 16 + lg * 4 + r][wc] = ps;
      }
  }
  // bf16 tile to LDS
#pragma unroll
  for (int m = 0; m < 4; ++m)
#pragma unroll
    for (int n = 0; n < 4; ++n)
#pragma unroll
      for (int r = 0; r < 4; ++r)
        smem[(wr * 64 + m * 16 + lg * 4 + r) * 130 + wc * 64 + n * 16 + lr] =
            f2bf(acc[m][n][r]);
  __syncthreads();
  const int tg0 = bm * 128;
  if (bn < 20) {
    const bool isq = bn < 16;
    const float* nw = isq ? qn_w : kn_w;
    const float qs = isq ? 0.12751744752f : 1.0f;  // 1/(sqrt(128)*ln2) for q
    u16* dstbase = isq ? (qh + (size_t)bn * 2048 * 128)
                       : (kh + (size_t)(bn - 16) * 2048 * 128);
    for (int it = 0; it < 64; ++it) {
      int idx = it * 256 + tid;
      int tl = idx >> 7, d = idx & 127;
      int tglob = tg0 + tl;
      int tt = tglob & 2047, bb = tglob >> 11;
      float rs = rsqrtf((ssbuf[tl][0] + ssbuf[tl][1]) * (1.0f / 128.0f) + 1e-6f);
      int d2 = (d + 64) & 127;
      float h1 = bf2f(smem[tl * 130 + d]) * rs * nw[d];
      float h2 = bf2f(smem[tl * 130 + d2]) * rs * nw[d2];
      float rot = (d < 64) ? -h2 : h2;
      float c = cosb[tt * 128 + d], s = sinb[tt * 128 + d];
      // q/k head layout: [(b*NH + head)*2048 + t]*128 + d
      u16* dst = dstbase + ((size_t)bb * (isq ? 16 : 4) * 2048 + (size_t)tt) * 128 + d;
      *dst = f2bf((h1 * c + rot * s) * qs);
    }
  } else {
    const int kvi = bn - 20;
    for (int it = 0; it < 64; ++it) {
      int idx = it * 256 + tid;
      int d = idx >> 7, tl = idx & 127;
      int tglob = tg0 + tl;
      int tt = tglob & 2047, bb = tglob >> 11;
      vt[((size_t)(bb * 4 + kvi) * 128 + d) * 2048 + tt] = smem[tl * 130 + d];
    }
  }
}

// ---------------- bf16 bt-GEMM (m97 structure, 128^2, XCD-localized) for GEMM2 --------
__global__ __launch_bounds__(256) void gemm_bt(
    const u16* __restrict__ A, const u16* __restrict__ B,
    float* __restrict__ C, int M, int N, int K) {
  __shared__ u16 As[128 * 32];
  __shared__ u16 Bs[128 * 32];
  const int tid = threadIdx.x;
  const int lin = blockIdx.x;
  const int x = lin & 7, t = lin >> 3;
  const int bm = x * 4 + (t & 3);
  const int bn = t >> 2;
  const int w = tid >> 6, l = tid & 63;
  const int wr = w >> 1, wc = w & 1;
  const int lr = l & 15, lg = l >> 4;
  f32x4 acc[4][4] = {};
  const int srow = tid >> 2;
  const int scol = (tid & 3) << 3;
  const u16* Ag = A + (size_t)bm * 128 * K + (size_t)srow * K + scol;
  const u16* Bg = B + (size_t)bn * 128 * K + (size_t)srow * K + scol;
  u16* Asl = As + srow * 32 + scol;
  u16* Bsl = Bs + srow * 32 + scol;
  const int nk = K >> 5;
  for (int kt = 0; kt < nk; ++kt) {
    __syncthreads();
    const int ko = kt << 5;
    load_lds16(Ag + ko, Asl);
    load_lds16(Ag + (size_t)64 * K + ko, Asl + 64 * 32);
    load_lds16(Bg + ko, Bsl);
    load_lds16(Bg + (size_t)64 * K + ko, Bsl + 64 * 32);
    __syncthreads();
    bf16x8 af[4], bfr[4];
#pragma unroll
    for (int m = 0; m < 4; ++m)
      af[m] = *(const bf16x8*)&As[(wr * 64 + m * 16 + lr) * 32 + lg * 8];
#pragma unroll
    for (int n = 0; n < 4; ++n)
      bfr[n] = *(const bf16x8*)&Bs[(wc * 64 + n * 16 + lr) * 32 + lg * 8];
#pragma unroll
    for (int m = 0; m < 4; ++m)
#pragma unroll
      for (int n = 0; n < 4; ++n)
        acc[m][n] = __builtin_amdgcn_mfma_f32_16x16x32_bf16(af[m], bfr[n], acc[m][n], 0, 0, 0);
  }
#pragma unroll
  for (int m = 0; m < 4; ++m) {
    const int row = bm * 128 + wr * 64 + m * 16 + lg * 4;
#pragma unroll
    for (int n = 0; n < 4; ++n) {
      const int col = bn * 128 + wc * 64 + n * 16 + lr;
#pragma unroll
      for (int r = 0; r < 4; ++r)
        C[(size_t)(row + r) * N + col] = acc[m][n][r];
    }
  }
}

// ---------------- causal GQA flash attention (R8 verified: 8-warp, log2 softmax) ------
__global__ __launch_bounds__(512, 2) void attn(
    const u16* __restrict__ qhat, const u16* __restrict__ khat,
    const u16* __restrict__ vT, u16* __restrict__ yb) {
  __shared__ u16 Kt[2][64 * 128];
  const int bi = blockIdx.x;           // bh*8 + s
  const int s = bi & 7;
  const int bh = bi >> 3;
  const int h = bh & 15, b = bh >> 4;
  const int kvh = h >> 2;
  const int tid = threadIdx.x;
  const int w = tid >> 6, l = tid & 63;
  const int ws = w & 3;
  const int cw = (w < 4) ? s : (15 - s);
  const int ql = l & 31, hi = l >> 5;
  const int wq0 = cw * 128 + ws * 32;
  const int wq_end = wq0 + 31;
  const int qg = wq0 + ql;

  bf16x8 qf[8];
  const u16* qp = qhat + ((size_t)(b * 16 + h) * 2048 + qg) * 128 + hi * 8;
#pragma unroll
  for (int sf = 0; sf < 8; ++sf) qf[sf] = *(const bf16x8*)(qp + 16 * sf);

  f32x16 yacc[4] = {};
  float m = -1e30f, lsum = 0.f;

  const u16* Kg = khat + (size_t)(b * 4 + kvh) * 2048 * 128;
  const u16* Vg = vT + (size_t)(b * 4 + kvh) * 128 * 2048;
  const int nt = 32 - 2 * s;

  auto stageK = [&](int tile, int buf) {
#pragma unroll
    for (int j = 0; j < 2; ++j) {
      int idx = j * 512 + tid;
      int row = idx >> 4, ch = idx & 15;
      load_lds16(Kg + (size_t)(tile * 64 + row) * 128 + ((ch ^ (row & 7)) * 8),
                 &Kt[buf][idx * 8]);
    }
  };

  stageK(0, 0);
  int cur = 0;
  for (int tile = 0; tile < nt; ++tile) {
    const int kv0 = tile * 64;
    __syncthreads();
    if (tile + 1 < nt) stageK(tile + 1, cur ^ 1);
    if (kv0 <= wq_end) {
      const u16* Vrow = Vg + (size_t)ql * 2048 + kv0 + hi * 8;
      bf16x8 vfr0[4], vfr1[4], vfr2[4], vfr3[4];
#pragma unroll
      for (int ks = 0; ks < 4; ++ks) vfr0[ks] = *(const bf16x8*)(Vrow + ks * 16);
#pragma unroll
      for (int ks = 0; ks < 4; ++ks) vfr1[ks] = *(const bf16x8*)(Vrow + 32 * 2048 + ks * 16);
#pragma unroll
      for (int ks = 0; ks < 4; ++ks) vfr2[ks] = *(const bf16x8*)(Vrow + 64 * 2048 + ks * 16);
#pragma unroll
      for (int ks = 0; ks < 4; ++ks) vfr3[ks] = *(const bf16x8*)(Vrow + 96 * 2048 + ks * 16);
      const u16* Kc = Kt[cur];
      f32x16 sacc[2] = {};
      __builtin_amdgcn_s_setprio(1);
#pragma unroll
      for (int n = 0; n < 2; ++n) {
#pragma unroll
        for (int sf = 0; sf < 8; ++sf) {
          bf16x8 kf = *(const bf16x8*)&Kc[(n * 32 + ql) * 128 + (((2 * sf + hi) ^ (l & 7)) * 8)];
          sacc[n] = __builtin_amdgcn_mfma_f32_32x32x16_bf16(kf, qf[sf], sacc[n], 0, 0, 0);
        }
      }
      __builtin_amdgcn_s_setprio(0);
      if (kv0 + 63 > wq0) {
#pragma unroll
        for (int n = 0; n < 2; ++n)
#pragma unroll
          for (int r = 0; r < 16; ++r) {
            int kv = kv0 + n * 32 + (r & 3) + 8 * (r >> 2) + 4 * hi;
            if (kv > qg) sacc[n][r] = -1e30f;
          }
      }
      float pm = -1e30f;
#pragma unroll
      for (int n = 0; n < 2; ++n)
#pragma unroll
        for (int r = 0; r < 16; ++r) pm = fmaxf(pm, sacc[n][r]);
      pm = fmaxf(pm, __shfl_xor(pm, 32));
      if (!__all(pm - m <= 11.0f)) {
        float mn = fmaxf(m, pm);
        float sc = exp2_fast(m - mn);
        m = mn;
        lsum *= sc;
#pragma unroll
        for (int r = 0; r < 16; ++r) {
          int row = (r & 3) + 8 * (r >> 2) + 4 * hi;
          float scr = __shfl(sc, row);
#pragma unroll
          for (int d = 0; d < 4; ++d) yacc[d][r] *= scr;
        }
      }
      float ls = 0.f;
#pragma unroll
      for (int n = 0; n < 2; ++n)
#pragma unroll
        for (int r = 0; r < 16; ++r) {
          float e = exp2_fast(sacc[n][r] - m);
          sacc[n][r] = e;
          ls += e;
        }
      ls += __shfl_xor(ls, 32);
      lsum += ls;
      bf16x8 pa[4];
#pragma unroll
      for (int s4 = 0; s4 < 4; ++s4) {
        const int n = s4 >> 1, R = (s4 & 1) * 8;
        unsigned P01 = cvtpk(sacc[n][R + 0], sacc[n][R + 1]);
        unsigned P23 = cvtpk(sacc[n][R + 2], sacc[n][R + 3]);
        unsigned P45 = cvtpk(sacc[n][R + 4], sacc[n][R + 5]);
        unsigned P67 = cvtpk(sacc[n][R + 6], sacc[n][R + 7]);
        plane32_swap(P01, P45);
        plane32_swap(P23, P67);
        union { u32x4 u; bf16x8 bv; } cvu;
        cvu.u[0] = P01; cvu.u[1] = P23; cvu.u[2] = P45; cvu.u[3] = P67;
        pa[s4] = cvu.bv;
      }
      __builtin_amdgcn_s_setprio(1);
#pragma unroll
      for (int ks = 0; ks < 4; ++ks) {
        yacc[0] = __builtin_amdgcn_mfma_f32_32x32x16_bf16(pa[ks], vfr0[ks], yacc[0], 0, 0, 0);
        yacc[1] = __builtin_amdgcn_mfma_f32_32x32x16_bf16(pa[ks], vfr1[ks], yacc[1], 0, 0, 0);
        yacc[2] = __builtin_amdgcn_mfma_f32_32x32x16_bf16(pa[ks], vfr2[ks], yacc[2], 0, 0, 0);
        yacc[3] = __builtin_amdgcn_mfma_f32_32x32x16_bf16(pa[ks], vfr3[ks], yacc[3], 0, 0, 0);
      }
      __builtin_amdgcn_s_setprio(0);
    }
    cur ^= 1;
  }
#pragma unroll
  for (int r = 0; r < 16; ++r) {
    int row = (r & 3) + 8 * (r >> 2) + 4 * hi;
    float li = __shfl(lsum, row);
    float inv = 1.0f / li;
    u16* yp = yb + ((size_t)(b * 2048) + wq0 + row) * 2048 + h * 128 + ql;
#pragma unroll
    for (int d = 0; d < 4; ++d) yp[d * 32] = f2bf(yacc[d][r] * inv);
  }
}

// ---------------- launcher ----------------

extern "C" void kernel_launch(void* const* d_in, const int* in_sizes, int n_in,
                              void* d_out, int out_size, void* d_ws, size_t ws_size,
                              hipStream_t stream) {
  const float* x    = (const float*)d_in[0];
  const float* Wq   = (const float*)d_in[1];
  const float* Wk   = (const float*)d_in[2];
  const float* Wv   = (const float*)d_in[3];
  const float* Wo   = (const float*)d_in[4];
  const float* qn   = (const float*)d_in[5];
  const float* kn   = (const float*)d_in[6];
  const float* cosb = (const float*)d_in[7];
  const float* sinb = (const float*)d_in[8];
  float* out = (float*)d_out;
  (void)in_sizes; (void)n_in; (void)out_size; (void)ws_size;

  char* p = (char*)d_ws;
  u16*   xb   = (u16*)p;   p += (size_t)8388608 * 2;    // x bf16 [4096,2048]
  u16*   wcat = (u16*)p;   p += (size_t)6291456 * 2;    // [3072,2048]
  u16*   wob  = (u16*)p;   p += (size_t)4194304 * 2;    // [2048,2048]
  u16*   qh   = (u16*)p;   p += (size_t)8388608 * 2;    // [2,16,2048,128]
  u16*   kh   = (u16*)p;   p += (size_t)2097152 * 2;    // [2,4,2048,128]
  u16*   vt   = (u16*)p;   p += (size_t)2097152 * 2;    // [2,4,128,2048]
  u16*   yb   = (u16*)p;   p += (size_t)8388608 * 2;    // [4096,2048]

  cvt_f32_bf16<<<2048, 256, 0, stream>>>(x, xb, 8388608);
  build_wcat<<<2048, 256, 0, stream>>>(Wq, Wk, Wv, wcat);
  cvt_f32_bf16<<<2048, 256, 0, stream>>>(Wo, wob, 4194304);
  gemm_qkv<<<768, 256, 0, stream>>>(xb, wcat, qn, kn, cosb, sinb, qh, kh, vt);
  attn<<<256, 512, 0, stream>>>(qh, kh, vt, yb);
  gemm_bt<<<512, 256, 0, stream>>>(yb, wob, out, 4096, 2048, 2048);
}